// Round 3
// baseline (601.031 us; speedup 1.0000x reference)
//
#include <hip/hip_runtime.h>

// Problem: B=4096, K=64, DIM=512, obj=0:
//   out = sum_{b, k != labels[b]} exp( -sum_d (inputs[b,d] - decoded[b,k,d])^2 )
//
// R3 (resubmit after infra failure): scattered+rotated probe window
// (DRAM-offset balance test).
//   R2 established the exact early-exit: expf(-x) == 0.0f exactly for
//   x >= 104 (e^-104 < 2^-150); fp32 partial sums of squares are monotone,
//   so a 128-dim probe reaching SKIP_T=128 proves the term is exactly 0.0f
//   and the rest of the row need not be read. P(probe < 128) ~ 3e-5 on
//   N(0,1)-scale data (~8 exact-fallback events per launch).
//
//   R2 probed dims [0,128) of every row -> every fetched address was
//   congruent to [0,512) mod 2048, using only 1/4 of the DRAM interleave
//   slots. R3 probes four 128-B chunks at 512-B stride, class-rotated per
//   row (c = (2j+g)&3), so fetched addresses cover all sixteen 128-B slots
//   of each 2-KiB row uniformly. Same bytes (146 MB), same statistics,
//   same exact fallback (full-row recompute).
//
//   Probed float4 slots for row k: {8c+s, 32+8c+s, 64+8c+s, 96+8c+s},
//   s=0..7, with c = (2j+g)&3. Lane m (half-wave): mh=m>>3 picks the
//   chunk, ml=m&7 the 16B within it; fo = 32*mh + ml + 8*g; class
//   alternation is compile-time per unrolled j (inA0 = class g,
//   inA1 = class g+2) so no runtime-indexed register arrays.

#define B_SZ 4096
#define K_SZ 64
#define DIM  512
#define ROW_F4 (DIM / 4)   // 128 float4 per decoded row
#define SKIP_T 128.0f

template <typename LT>
__global__ __launch_bounds__(256) void score_kernel(
    const float* __restrict__ inputs,   // (B, DIM)
    const float* __restrict__ decoded,  // (B, K, DIM)
    const LT*    __restrict__ labels,   // (B,)
    float* __restrict__ partials)       // (B,) in workspace
{
    const int b    = blockIdx.x;
    const int tid  = threadIdx.x;
    const int wave = tid >> 6;   // 0..3
    const int lane = tid & 63;
    const int m    = lane & 31;  // lane within half-wave
    const int g    = lane >> 5;  // half-wave group 0/1
    const int mh   = m >> 3;     // chunk slot 0..3 (512B-strided chunks)
    const int ml   = m & 7;      // 16B slot within 128-B chunk

    const float4* inp = (const float4*)(inputs + (size_t)b * DIM);

    // Per-lane float4 base slot within a row for class g / class g+2.
    const int fo = 32 * mh + ml + 8 * g;       // < 104
    const float4 inA0 = inp[fo];               // input frag, class g
    const float4 inA1 = inp[fo + 16];          // input frag, class g+2

    const int lab = (int)labels[b];
    const float4* dec = (const float4*)(decoded + (size_t)b * K_SZ * DIM);

    // Wave w owns k = 16w..16w+15; iteration j: half g covers k = 16w+2j+g.
    const int kbase = wave * 16 + g;

    // Phase A: pure streaming — 8 independent dwordx4 loads per lane.
    float s[8];
    #pragma unroll
    for (int j = 0; j < 8; ++j) {
        const int k = kbase + 2 * j;
        const float4 d = dec[(size_t)k * ROW_F4 + fo + ((j & 1) << 4)];
        const float4 iv = (j & 1) ? inA1 : inA0;   // compile-time select
        float dx, t;
        dx = iv.x - d.x; t  = dx * dx;
        dx = iv.y - d.y; t += dx * dx;
        dx = iv.z - d.z; t += dx * dx;
        dx = iv.w - d.w; t += dx * dx;
        s[j] = t;
    }

    // Phase B: 8 independent 5-stage butterflies (stay inside 32-lane half).
    #pragma unroll
    for (int j = 0; j < 8; ++j) {
        float t = s[j];
        #pragma unroll
        for (int off = 16; off; off >>= 1)
            t += __shfl_xor(t, off, 64);
        s[j] = t;   // s_128 for this half's row k = kbase + 2j
    }

    // Phase C: threshold; probe >= SKIP_T  =>  exact 0.0f contribution.
    float acc = 0.0f;
    #pragma unroll
    for (int j = 0; j < 8; ++j) {
        const int k = kbase + 2 * j;
        float sv = s[j];
        if (__any(sv < SKIP_T)) {            // ~never taken (P ~ 3e-5/row)
            // Exact fallback: recompute the full 512-dim distance.
            const float4* rowt = dec + (size_t)k * ROW_F4;
            float t = 0.0f;
            #pragma unroll
            for (int c = 0; c < 4; ++c) {
                const float4 dv = rowt[c * 32 + m];
                const float4 iv = inp[c * 32 + m];
                float dx;
                dx = iv.x - dv.x; t += dx * dx;
                dx = iv.y - dv.y; t += dx * dx;
                dx = iv.z - dv.z; t += dx * dx;
                dx = iv.w - dv.w; t += dx * dx;
            }
            #pragma unroll
            for (int off = 16; off; off >>= 1)
                t += __shfl_xor(t, off, 64);
            sv = t;                          // exact full fp32 distance
        }
        if (sv < SKIP_T && k != lab) acc += expf(-sv);
    }

    // acc is half-wave-uniform; halves cover disjoint k's -> wave total.
    acc += __shfl_xor(acc, 32, 64);

    __shared__ float wacc[4];
    if (lane == 0) wacc[wave] = acc;
    __syncthreads();
    if (tid == 0) partials[b] = wacc[0] + wacc[1] + wacc[2] + wacc[3];
}

__global__ __launch_bounds__(256) void reduce_kernel(
    const float* __restrict__ partials, float* __restrict__ out)
{
    const float4* p4 = (const float4*)partials;   // 1024 float4
    float s = 0.0f;
    for (int i = threadIdx.x; i < B_SZ / 4; i += 256) {
        const float4 v = p4[i];
        s += (v.x + v.y) + (v.z + v.w);
    }
    #pragma unroll
    for (int off = 32; off; off >>= 1)
        s += __shfl_xor(s, off, 64);
    __shared__ float wacc[4];
    const int wave = threadIdx.x >> 6, lane = threadIdx.x & 63;
    if (lane == 0) wacc[wave] = s;
    __syncthreads();
    if (threadIdx.x == 0) out[0] = wacc[0] + wacc[1] + wacc[2] + wacc[3];
}

extern "C" void kernel_launch(void* const* d_in, const int* in_sizes, int n_in,
                              void* d_out, int out_size, void* d_ws, size_t ws_size,
                              hipStream_t stream) {
    const float* inputs  = (const float*)d_in[0];
    const float* decoded = (const float*)d_in[1];
    // d_in[3] is obj (==0 in setup) -> obj=False branch implemented.
    float* out      = (float*)d_out;
    float* partials = (float*)d_ws;   // B_SZ floats, fully overwritten each call

    // Reference declares labels int64; be dtype-robust via in_sizes.
    if (in_sizes[2] >= (int)(B_SZ * sizeof(long long))) {
        score_kernel<long long><<<B_SZ, 256, 0, stream>>>(
            inputs, decoded, (const long long*)d_in[2], partials);
    } else {
        score_kernel<int><<<B_SZ, 256, 0, stream>>>(
            inputs, decoded, (const int*)d_in[2], partials);
    }
    reduce_kernel<<<1, 256, 0, stream>>>(partials, out);
}

// Round 4
// 588.930 us; speedup vs baseline: 1.0205x; 1.0205x over previous
//
#include <hip/hip_runtime.h>

// Problem: B=4096, K=64, DIM=512, obj=0:
//   out = sum_{b, k != labels[b]} exp( -sum_d (inputs[b,d] - decoded[b,k,d])^2 )
//
// R4: two-stage cascade probe (byte-optimal exact early-exit).
//   Exactness basis (R2): expf(-x) == 0.0f for x >= 104 (e^-104 < half the
//   smallest fp32 subnormal); fp32 sums of squares are monotone
//   non-decreasing, so any partial sum reaching SKIP_T=104 proves the term
//   is exactly 0 (up to <=1.4e-45 reference bit-noise) and the rest of the
//   row need not be read.
//
//   Cascade (s_D ~ 2*chi2_D on N(0,1)-scale data):
//     stage 1: 64-dim probe, all rows.        P(fail) ~ 0.141
//     stage 2: extend to 128 dims, failures.  P(fail) ~ 3e-10
//     stage 3: full 512-dim exact recompute.  ~never (correctness only)
//   Expected traffic: 67.1 MB + 0.141*9.4 MB + ~2 MB inputs ~ 79 MB
//   (vs 146 MB single-stage 128-dim probe). R3 established address
//   distribution within rows is irrelevant (R2 vs R3 identical).
//
//   Layout: 4 rows per wave per iteration in 16-lane groups (ALL 64 lanes
//   active). Group q=lane>>4 handles k = 16*wave + 4j + q; lane m16=lane&15
//   loads float4 slot m16 (dims 4*m16..4*m16+3). Butterflies are 4-stage,
//   offsets 8..1, confined to the 16-lane group (no masked-partner hazard:
//   stage-2/3 predicates are group-uniform). Streaming phase is branch-free
//   (R1 structure): all stage-1 loads issue before any shfl/branch.

#define B_SZ 4096
#define K_SZ 64
#define DIM  512
#define ROW_F4 (DIM / 4)   // 128 float4 per decoded row
#define SKIP_T 104.0f      // exact fp32 underflow bound for expf(-x)

template <typename LT>
__global__ __launch_bounds__(256) void score_kernel(
    const float* __restrict__ inputs,   // (B, DIM)
    const float* __restrict__ decoded,  // (B, K, DIM)
    const LT*    __restrict__ labels,   // (B,)
    float* __restrict__ partials)       // (B,) in workspace
{
    const int b    = blockIdx.x;
    const int tid  = threadIdx.x;
    const int wave = tid >> 6;        // 0..3
    const int lane = tid & 63;
    const int q    = (lane >> 4) & 3; // 16-lane group 0..3
    const int m16  = lane & 15;       // lane within group

    const float4* inp = (const float4*)(inputs + (size_t)b * DIM);
    const float4 in1 = inp[m16];       // dims [0,64)   : stage-1 fragment
    const float4 in2 = inp[16 + m16];  // dims [64,128) : stage-2 fragment

    const int lab = (int)labels[b];
    const float4* dec = (const float4*)(decoded + (size_t)b * K_SZ * DIM);

    // Group q of wave w covers k = 16w + 4j + q, j = 0..3.
    const int kbase = wave * 16 + q;

    // Phase A: branch-free streaming — 4 independent dwordx4 loads/lane.
    float s[4];
    #pragma unroll
    for (int j = 0; j < 4; ++j) {
        const float4 d = dec[(size_t)(kbase + 4 * j) * ROW_F4 + m16];
        float dx, t;
        dx = in1.x - d.x; t  = dx * dx;
        dx = in1.y - d.y; t += dx * dx;
        dx = in1.z - d.z; t += dx * dx;
        dx = in1.w - d.w; t += dx * dx;
        s[j] = t;
    }

    // Phase B: 4 independent 4-stage butterflies (within 16-lane group).
    #pragma unroll
    for (int j = 0; j < 4; ++j) {
        float t = s[j];
        #pragma unroll
        for (int off = 8; off; off >>= 1)
            t += __shfl_xor(t, off, 64);
        s[j] = t;   // s_64 for row kbase+4j, group-uniform
    }

    // Phase C: cascade. Partial >= SKIP_T  =>  exact 0.0f contribution.
    float acc = 0.0f;
    #pragma unroll
    for (int j = 0; j < 4; ++j) {
        const int k = kbase + 4 * j;
        const float4* row = dec + (size_t)k * ROW_F4;
        float sv = s[j];

        if (__any(sv < SKIP_T)) {                 // ~43% of wave-iters
            // Stage 2: extend failing groups to 128 dims (exec-masked load).
            float t2 = 0.0f;
            if (sv < SKIP_T) {                    // group-uniform predicate
                const float4 d2 = row[16 + m16];
                float dx;
                dx = in2.x - d2.x; t2  = dx * dx;
                dx = in2.y - d2.y; t2 += dx * dx;
                dx = in2.z - d2.z; t2 += dx * dx;
                dx = in2.w - d2.w; t2 += dx * dx;
            }
            #pragma unroll
            for (int off = 8; off; off >>= 1)     // all lanes; zeros for
                t2 += __shfl_xor(t2, off, 64);    // passing groups
            sv += t2;                             // s_128 for failing groups

            if (__any(sv < SKIP_T)) {             // P ~ 3e-10 per row
                // Stage 3: full 512-dim exact recompute (correctness only).
                float t3 = 0.0f;
                if (sv < SKIP_T) {
                    #pragma unroll
                    for (int c = 0; c < 8; ++c) {
                        const float4 dv = row[c * 16 + m16];
                        const float4 iv = inp[c * 16 + m16];
                        float dx;
                        dx = iv.x - dv.x; t3 += dx * dx;
                        dx = iv.y - dv.y; t3 += dx * dx;
                        dx = iv.z - dv.z; t3 += dx * dx;
                        dx = iv.w - dv.w; t3 += dx * dx;
                    }
                }
                #pragma unroll
                for (int off = 8; off; off >>= 1)
                    t3 += __shfl_xor(t3, off, 64);
                if (sv < SKIP_T) sv = t3;         // exact full distance
            }
        }
        if (sv < SKIP_T && k != lab) acc += expf(-sv);
    }

    // acc is group-uniform; groups cover disjoint k's. Sum the 4 groups:
    acc += __shfl_xor(acc, 16, 64);
    acc += __shfl_xor(acc, 32, 64);   // wave total, uniform across wave

    __shared__ float wacc[4];
    if (lane == 0) wacc[wave] = acc;
    __syncthreads();
    if (tid == 0) partials[b] = wacc[0] + wacc[1] + wacc[2] + wacc[3];
}

__global__ __launch_bounds__(256) void reduce_kernel(
    const float* __restrict__ partials, float* __restrict__ out)
{
    const float4* p4 = (const float4*)partials;   // 1024 float4
    float s = 0.0f;
    for (int i = threadIdx.x; i < B_SZ / 4; i += 256) {
        const float4 v = p4[i];
        s += (v.x + v.y) + (v.z + v.w);
    }
    #pragma unroll
    for (int off = 32; off; off >>= 1)
        s += __shfl_xor(s, off, 64);
    __shared__ float wacc[4];
    const int wave = threadIdx.x >> 6, lane = threadIdx.x & 63;
    if (lane == 0) wacc[wave] = s;
    __syncthreads();
    if (threadIdx.x == 0) out[0] = wacc[0] + wacc[1] + wacc[2] + wacc[3];
}

extern "C" void kernel_launch(void* const* d_in, const int* in_sizes, int n_in,
                              void* d_out, int out_size, void* d_ws, size_t ws_size,
                              hipStream_t stream) {
    const float* inputs  = (const float*)d_in[0];
    const float* decoded = (const float*)d_in[1];
    // d_in[3] is obj (==0 in setup) -> obj=False branch implemented.
    float* out      = (float*)d_out;
    float* partials = (float*)d_ws;   // B_SZ floats, fully overwritten each call

    // Reference declares labels int64; be dtype-robust via in_sizes.
    if (in_sizes[2] >= (int)(B_SZ * sizeof(long long))) {
        score_kernel<long long><<<B_SZ, 256, 0, stream>>>(
            inputs, decoded, (const long long*)d_in[2], partials);
    } else {
        score_kernel<int><<<B_SZ, 256, 0, stream>>>(
            inputs, decoded, (const int*)d_in[2], partials);
    }
    reduce_kernel<<<1, 256, 0, stream>>>(partials, out);
}